// Round 7
// baseline (239.085 us; speedup 1.0000x reference)
//
#include <hip/hip_runtime.h>
#include <hip/hip_bf16.h>

typedef unsigned short u16;
typedef unsigned int u32;
typedef __attribute__((ext_vector_type(8))) short bh8;   // 8 bf16 (MFMA A/B frag)
typedef __attribute__((ext_vector_type(4))) short sh4;   // 4 bf16 (8B store)
typedef __attribute__((ext_vector_type(4))) float f4;    // MFMA C/D frag

#define T_   4
#define B_   16
#define C_   512
#define N_   256
#define M2_  4096

// ---------------- helpers ----------------
__device__ __forceinline__ u16 f2bf(float f) {
  u32 u = __float_as_uint(f);
  u32 r = (u + 0x7FFFu + ((u >> 16) & 1u)) >> 16;   // RNE
  return (u16)r;
}
__device__ __forceinline__ void gl_lds16(const void* g, void* l) {
  __builtin_amdgcn_global_load_lds(
      (const __attribute__((address_space(1))) unsigned int*)g,
      (__attribute__((address_space(3))) unsigned int*)l, 16, 0, 0);
}

// ---------------- K0: merged {weight split (branch-interleaved) + BN consts} + {shortcut LIF} ----------------
// WCAT row layout: rI = (o/32)*96 + branch*32 + (o%32)  -> each 96-row tile = {q,k,v} x 32 channels
__global__ void k_prep_lif(const float* __restrict__ x, u16* __restrict__ xs,
                           const float* __restrict__ wq, const float* __restrict__ wk,
                           const float* __restrict__ wv, const float* __restrict__ wp,
                           const float* qg, const float* qb, const float* qm, const float* qv,
                           const float* kg, const float* kb, const float* km, const float* kv2,
                           const float* vg, const float* vb, const float* vm, const float* vv,
                           const float* pg, const float* pb, const float* pm, const float* pv,
                           const float* bp,
                           u16* __restrict__ wcat, u16* __restrict__ wpcat,
                           float* bns, float* pss) {
  __shared__ u16 sp[4][64][68];
  int bid = blockIdx.x;
  int tid = threadIdx.x;
  if (bid < 512) {
    int b = bid >> 5, c0 = ((bid >> 2) & 7) * 64, n0 = (bid & 3) * 64;
    int rq = tid >> 4;
    int n4 = (tid & 15) * 4;
    f4 xr[4][4];
#pragma unroll
    for (int t = 0; t < 4; t++) {
      const float* xb = x + (((size_t)t * 16 + b) * 512 + c0) * 256 + n0;
#pragma unroll
      for (int i = 0; i < 4; i++)
        xr[t][i] = *(const f4*)(xb + (size_t)(rq + i * 16) * 256 + n4);
    }
    float v[16];
#pragma unroll
    for (int i = 0; i < 16; i++) v[i] = 0.f;
#pragma unroll
    for (int t = 0; t < 4; t++) {
#pragma unroll
      for (int i = 0; i < 4; i++) {
        int row = rq + i * 16;
        sh4 sv;
#pragma unroll
        for (int j = 0; j < 4; j++) {
          float vv2 = v[i * 4 + j];
          vv2 = vv2 + (xr[t][i][j] - vv2) * 0.5f;
          u16 s = 0;
          if (vv2 >= 1.0f) { s = 0x3F80; vv2 = 0.f; }
          v[i * 4 + j] = vv2;
          sv[j] = (short)s;
        }
        *(sh4*)&sp[t][row][n4] = sv;
      }
    }
    __syncthreads();
    int cp = (tid & 31) * 2;
    int nq = tid >> 5;
    for (int t = 0; t < 4; t++) {
      u16* ob = xs + (((size_t)t * 16 + b) * 256 + n0) * 512 + c0;
#pragma unroll
      for (int i = 0; i < 8; i++) {
        int n = nq + i * 8;
        u32 w = (u32)sp[t][cp][n] | ((u32)sp[t][cp + 1][n] << 16);
        *(u32*)(ob + (size_t)n * 512 + cp) = w;
      }
    }
  } else {
    int id = (bid - 512) * 256 + tid;
    if (id < 1048576) {
      int mat = id >> 18;
      int rc  = id & 262143;
      int o = rc >> 9, c = rc & 511;
      const float* src = (mat == 0) ? wq : (mat == 1) ? wk : (mat == 2) ? wv : wp;
      float w = src[rc];
      u16 hu = f2bf(w);
      float hf = __uint_as_float(((u32)hu) << 16);
      u16 lu = f2bf(w - hf);
      if (mat < 3) {
        int rI = (o >> 5) * 96 + mat * 32 + (o & 31);   // branch-interleaved row
        size_t base = (size_t)rI * 1024 + c;
        wcat[base] = hu; wcat[base + 512] = lu;
      } else {
        size_t base = (size_t)o * 1024 + c;
        wpcat[base] = hu; wpcat[base + 512] = lu;
      }
    } else {
      int j = id - 1048576;
      if (j < 1536) {
        int br = j >> 9, o = j & 511;
        const float *g, *b, *m, *va;
        if (br == 0)      { g = qg; b = qb; m = qm; va = qv; }
        else if (br == 1) { g = kg; b = kb; m = km; va = kv2; }
        else              { g = vg; b = vb; m = vm; va = vv; }
        float s = g[o] / sqrtf(va[o] + 1e-5f);
        int rI = (o >> 5) * 96 + br * 32 + (o & 31);
        bns[rI * 4 + 0] = s; bns[rI * 4 + 1] = m[o]; bns[rI * 4 + 2] = b[o];
        bns[rI * 4 + 3] = 0.f;
      } else if (j < 2048) {
        int c = j - 1536;
        float s = pg[c] / sqrtf(pv[c] + 1e-5f);
        pss[c * 4 + 0] = bp[c]; pss[c * 4 + 1] = pm[c];
        pss[c * 4 + 2] = s;     pss[c * 4 + 3] = pb[c];
      }
    }
  }
}

// ---------------- K2: fused QKV GEMM + BN + LIF + kv-count + vout, k-split waves ----------------
// 128x96 tile, BK=64, dbuf 2x40KB. Waves: mw = wid&1 (64-row half), kw = wid>>1 (32-k half).
// Per step each wave reads 16 frags (vs 28) -> 1.75x less LDS read traffic.
// At ks==7: kw1 partial accs merged into kw0 via dead LDS buffer (2 x 24KB f32 phases).
__launch_bounds__(256, 2)
__global__ void k_qkv_gemm(const u16* __restrict__ xs, const u16* __restrict__ wcat,
                           const float* __restrict__ bns,
                           u16* __restrict__ qs, float* __restrict__ vout,
                           int* __restrict__ kvp) {
  __shared__ char lds[81920];   // buf: A 16K | Bh 12K | Bl 12K ; x2
  int tid = threadIdx.x, lane = tid & 63;
  int wid = tid >> 6;
  int mw = wid & 1, kw = wid >> 1;
  int lr = lane & 15, lq = lane >> 4;
  int m0 = blockIdx.x * 128;
  int cb = blockIdx.y;
  int o0 = cb * 96;
  int b = m0 >> 8, n0 = m0 & 255, half = (m0 >> 7) & 1;

  int srow = tid >> 3;
  u32 sgoff = (u32)(((tid & 7) ^ (srow & 7)) << 4);
  u32 ldst = (u32)tid * 16;

  u32 aoff[4], boff[6];
#pragma unroll
  for (int mi = 0; mi < 4; mi++) {
    int r = mw * 64 + mi * 16 + lr;
    aoff[mi] = r * 128 + (((lq ^ (r & 7)) ^ (kw << 2)) << 4);
  }
#pragma unroll
  for (int ni = 0; ni < 6; ni++) {
    int r = ni * 16 + lr;
    boff[ni] = r * 128 + (((lq ^ (r & 7)) ^ (kw << 2)) << 4);
  }

  const char* Bb = (const char*)wcat + (size_t)o0 * 2048;

  auto STAGE = [&](int buf, int step) {
    int t = step >> 3;
    u32 kb = (u32)(step & 7) * 128;
    const char* Ab = (const char*)xs + ((size_t)t * M2_ + m0) * 1024;
    char* L = lds + buf * 40960;
#pragma unroll
    for (int r2 = 0; r2 < 4; r2++)
      gl_lds16(Ab + (size_t)(r2 * 32 + srow) * 1024 + kb + sgoff, L + r2 * 4096 + ldst);
#pragma unroll
    for (int r2 = 0; r2 < 3; r2++) {
      gl_lds16(Bb + (size_t)(r2 * 32 + srow) * 2048 + kb + sgoff, L + 16384 + r2 * 4096 + ldst);
      gl_lds16(Bb + (size_t)(r2 * 32 + srow) * 2048 + 1024 + kb + sgoff, L + 28672 + r2 * 4096 + ldst);
    }
  };

  float vst[4][6][4];   // LIF membrane, meaningful on kw==0 waves
#pragma unroll
  for (int a = 0; a < 4; a++)
#pragma unroll
    for (int bq = 0; bq < 6; bq++)
#pragma unroll
      for (int c = 0; c < 4; c++) vst[a][bq][c] = 0.f;

  f4 acc[4][6];
  STAGE(0, 0);
  __syncthreads();                 // drain prologue stage
  int cur = 0;
  for (int step = 0; step < 32; ++step) {
    int ks = step & 7;
    if (ks == 0) {
#pragma unroll
      for (int a = 0; a < 4; a++)
#pragma unroll
        for (int bq = 0; bq < 6; bq++) { acc[a][bq][0] = 0.f; acc[a][bq][1] = 0.f; acc[a][bq][2] = 0.f; acc[a][bq][3] = 0.f; }
    }
    if (step < 31) STAGE(cur ^ 1, step + 1);   // next-tile loads in flight across MFMAs
    const char* L = lds + cur * 40960;
    bh8 af[4];
#pragma unroll
    for (int mi = 0; mi < 4; mi++)
      af[mi] = *(const bh8*)(L + aoff[mi]);
#pragma unroll
    for (int ni = 0; ni < 6; ni++) {
      bh8 bf = *(const bh8*)(L + 16384 + boff[ni]);
      bh8 lf = *(const bh8*)(L + 28672 + boff[ni]);
#pragma unroll
      for (int mi = 0; mi < 4; mi++)
        acc[mi][ni] = __builtin_amdgcn_mfma_f32_16x16x32_bf16(af[mi], bf, acc[mi][ni], 0, 0, 0);
#pragma unroll
      for (int mi = 0; mi < 4; mi++)
        acc[mi][ni] = __builtin_amdgcn_mfma_f32_16x16x32_bf16(af[mi], lf, acc[mi][ni], 0, 0, 0);
    }
    asm volatile("s_waitcnt vmcnt(0)" ::: "memory");   // next-tile loads landed
    __builtin_amdgcn_s_barrier();
    cur ^= 1;
    if (ks == 7) {
      int t = step >> 3;
      char* dead = lds + (cur ^ 1) * 40960;   // just-read buffer (free scratch)
      // ---- merge kw1 partial accs into kw0 (two 24KB phases) ----
#pragma unroll
      for (int p = 0; p < 2; p++) {
        if (kw == 1) {
#pragma unroll
          for (int m2 = 0; m2 < 2; m2++)
#pragma unroll
            for (int ni = 0; ni < 6; ni++)
              *(f4*)(dead + (((mw * 12 + m2 * 6 + ni) * 64 + lane) << 4)) = acc[p * 2 + m2][ni];
        }
        asm volatile("s_waitcnt lgkmcnt(0)" ::: "memory");
        __builtin_amdgcn_s_barrier();
        if (kw == 0) {
#pragma unroll
          for (int m2 = 0; m2 < 2; m2++)
#pragma unroll
            for (int ni = 0; ni < 6; ni++) {
              f4 o = *(const f4*)(dead + (((mw * 12 + m2 * 6 + ni) * 64 + lane) << 4));
              acc[p * 2 + m2][ni][0] += o[0];
              acc[p * 2 + m2][ni][1] += o[1];
              acc[p * 2 + m2][ni][2] += o[2];
              acc[p * 2 + m2][ni][3] += o[3];
            }
        }
        asm volatile("s_waitcnt lgkmcnt(0)" ::: "memory");
        __builtin_amdgcn_s_barrier();
      }
      // ---- BN + LIF on kw0 waves (rows mw*64..mw*64+63) ----
      unsigned char* vbuf = (unsigned char*)dead;           // [128][32] u8
      short* cbuf = (short*)(dead + 4096);                  // [128][2]
      if (kw == 0) {
        int cnt0 = 0, cnt1 = 0;
        u16 kbits[4]; kbits[0] = 0; kbits[1] = 0; kbits[2] = 0; kbits[3] = 0;
#pragma unroll
        for (int ni = 0; ni < 6; ni++) {
          int rI = o0 + ni * 16 + lr;
          f4 bn4 = *(const f4*)&bns[rI * 4];   // {scl, mean, beta, 0}
          int jj = ni & 1;
#pragma unroll
          for (int mi = 0; mi < 4; mi++) {
#pragma unroll
            for (int j = 0; j < 4; j++) {
              float y = (acc[mi][ni][j] - bn4[1]) * bn4[0] + bn4[2];
              float vv = vst[mi][ni][j];
              vv = vv + (y - vv) * 0.5f;
              int s = (vv >= 1.0f) ? 1 : 0;
              if (s) vv = 0.f;
              vst[mi][ni][j] = vv;
              if (ni < 2) {                 // q spikes -> QS
                int rg = m0 + mw * 64 + mi * 16 + lq * 4 + j;
                int cc = cb * 32 + jj * 16 + lr;
                qs[((size_t)t * M2_ + rg) * 512 + cc] = s ? (u16)0x3F80 : (u16)0;
              } else if (ni < 4) {          // k spikes -> bits
                kbits[mi] |= (u16)(s << (jj * 4 + j));
              } else {                      // v spikes -> vbuf + kv count
                int row = mw * 64 + mi * 16 + lq * 4 + j;
                vbuf[row * 32 + jj * 16 + lr] = (unsigned char)s;
                int kbit = (kbits[mi] >> (jj * 4 + j)) & 1;
                if (jj == 0) cnt0 += (s & kbit); else cnt1 += (s & kbit);
              }
            }
          }
        }
        cbuf[tid * 2] = (short)cnt0; cbuf[tid * 2 + 1] = (short)cnt1;
      }
      asm volatile("s_waitcnt lgkmcnt(0)" ::: "memory");
      __builtin_amdgcn_s_barrier();
      // ---- phase B: coalesced vout flush + kv partial write (all 256 threads) ----
      {
        int d0 = (cb & 1) * 32;
        int hh = cb >> 1;
        float* vo = vout + (((size_t)(t * 16 + b) * 8 + hh) * 256 + n0) * 64 + d0;
#pragma unroll
        for (int p = 0; p < 4; p++) {
          int row = (tid >> 3) + p * 32;
          const unsigned char* src = vbuf + row * 32 + (tid & 7) * 4;
          f4 w2; w2[0] = src[0]; w2[1] = src[1]; w2[2] = src[2]; w2[3] = src[3];
          *(f4*)(vo + (size_t)row * 64 + (tid & 7) * 4) = w2;
        }
        if (tid < 32) {
          int lr2 = tid & 15, jj = tid >> 4;
          int ssum = 0;
#pragma unroll
          for (int w3 = 0; w3 < 2; w3++)
#pragma unroll
            for (int q3 = 0; q3 < 4; q3++)
              ssum += cbuf[(w3 * 64 + q3 * 16 + lr2) * 2 + jj];
          kvp[(((t * 16 + b) * 2 + half) << 9) + cb * 32 + jj * 16 + lr2] = ssum;
        }
      }
      asm volatile("s_waitcnt lgkmcnt(0)" ::: "memory");
      __builtin_amdgcn_s_barrier();
    }
  }
}

// ---------------- K5: proj GEMM with in-block talking-heads LIF mask + fused epilogue ----------------
__launch_bounds__(256, 2)
__global__ void k_proj_gemm(const u16* __restrict__ qs, const int* __restrict__ kvp,
                            const u16* __restrict__ wpc, const float* __restrict__ pss,
                            const float* __restrict__ x, float* __restrict__ out) {
  __shared__ char lds[66560];   // buf: A 16K | Bh 8K | Bl 8K ; x2 = 64K ; lm at 65536
  u16* lm = (u16*)(lds + 65536);
  int tid = threadIdx.x, lane = tid & 63, wid = tid >> 6;
  int wr = wid >> 1, wc = wid & 1, lr = lane & 15, lq = lane >> 4;
  int m0 = blockIdx.x * 128, o0 = blockIdx.y * 64;
  int tb = m0 >> 8;

  // in-block talking-heads LIF: recompute mask for this tb from KVP partials
  {
    int b_ = tb & 15, tt = tb >> 4;
#pragma unroll
    for (int ci = 0; ci < 2; ci++) {
      int cc = tid + ci * 256;
      float v = 0.f; u16 mk = 0;
#pragma unroll
      for (int t2 = 0; t2 < 4; t2++) {
        int tb2 = t2 * 16 + b_;
        int s = kvp[((tb2 * 2) << 9) + cc] + kvp[((tb2 * 2 + 1) << 9) + cc];
        v = v + ((float)s - v) * 0.5f;
        int sp = (v >= 0.5f) ? 1 : 0;
        if (sp) v = 0.f;
        if (t2 == tt) mk = sp ? (u16)0xFFFF : (u16)0;
      }
      lm[cc] = mk;
    }
  }

  int srow = tid >> 3;
  u32 sgoff = (u32)(((tid & 7) ^ (srow & 7)) << 4);
  u32 ldst = (u32)tid * 16;

  u32 aoff[4], boff[2];
#pragma unroll
  for (int mi = 0; mi < 4; mi++) {
    int r = wr * 64 + mi * 16 + lr;
    aoff[mi] = r * 128 + ((lq ^ (r & 7)) << 4);
  }
#pragma unroll
  for (int ni = 0; ni < 2; ni++) {
    int r = wc * 32 + ni * 16 + lr;
    boff[ni] = r * 128 + ((lq ^ (r & 7)) << 4);
  }

  const char* Ab = (const char*)qs + (size_t)m0 * 1024;
  const char* Bb = (const char*)wpc + (size_t)o0 * 2048;

  auto STAGE = [&](int buf, int step) {
    u32 kb = (u32)step * 128;
    char* L = lds + buf * 32768;
#pragma unroll
    for (int r2 = 0; r2 < 4; r2++)
      gl_lds16(Ab + (size_t)(r2 * 32 + srow) * 1024 + kb + sgoff, L + r2 * 4096 + ldst);
#pragma unroll
    for (int r2 = 0; r2 < 2; r2++) {
      gl_lds16(Bb + (size_t)(r2 * 32 + srow) * 2048 + kb + sgoff, L + 16384 + r2 * 4096 + ldst);
      gl_lds16(Bb + (size_t)(r2 * 32 + srow) * 2048 + 1024 + kb + sgoff, L + 24576 + r2 * 4096 + ldst);
    }
  };

  f4 acc[4][2];
#pragma unroll
  for (int a = 0; a < 4; a++)
#pragma unroll
    for (int b2 = 0; b2 < 2; b2++) { acc[a][b2][0] = 0.f; acc[a][b2][1] = 0.f; acc[a][b2][2] = 0.f; acc[a][b2][3] = 0.f; }

  STAGE(0, 0);
  __syncthreads();                 // drain prologue stage + publish lm
  int cur = 0;
  for (int step = 0; step < 8; ++step) {
    u32 kb = (u32)step * 128;
    if (step < 7) STAGE(cur ^ 1, step + 1);
    const char* L = lds + cur * 32768;
#pragma unroll
    for (int h = 0; h < 2; h++) {
      u32 hx = (u32)h << 6;
      bh8 mq = *(const bh8*)((const char*)lm + kb + (h << 6) + lq * 16);
      bh8 af[4], bf[2], lf[2];
#pragma unroll
      for (int mi = 0; mi < 4; mi++) {
        af[mi] = *(const bh8*)(L + (aoff[mi] ^ hx));
        af[mi] = af[mi] & mq;
      }
#pragma unroll
      for (int ni = 0; ni < 2; ni++) {
        bf[ni] = *(const bh8*)(L + 16384 + (boff[ni] ^ hx));
        lf[ni] = *(const bh8*)(L + 24576 + (boff[ni] ^ hx));
      }
#pragma unroll
      for (int mi = 0; mi < 4; mi++)
#pragma unroll
        for (int ni = 0; ni < 2; ni++)
          acc[mi][ni] = __builtin_amdgcn_mfma_f32_16x16x32_bf16(af[mi], bf[ni], acc[mi][ni], 0, 0, 0);
#pragma unroll
      for (int mi = 0; mi < 4; mi++)
#pragma unroll
        for (int ni = 0; ni < 2; ni++)
          acc[mi][ni] = __builtin_amdgcn_mfma_f32_16x16x32_bf16(af[mi], lf[ni], acc[mi][ni], 0, 0, 0);
    }
    asm volatile("s_waitcnt vmcnt(0)" ::: "memory");
    __builtin_amdgcn_s_barrier();
    cur ^= 1;
  }
  // fused epilogue: BN(y + bp) + identity, transposed store to out[tb][o][n]
#pragma unroll
  for (int mi = 0; mi < 4; mi++)
#pragma unroll
    for (int ni = 0; ni < 2; ni++) {
      int o = o0 + wc * 32 + ni * 16 + lr;
      f4 ps = *(const f4*)&pss[o * 4];        // {bp, pm, scale, beta}
      int n = (m0 & 255) + wr * 64 + mi * 16 + lq * 4;
      size_t idx = (size_t)tb * 131072 + (size_t)o * 256 + n;
      f4 xv = *(const f4*)&x[idx];
      f4 res;
#pragma unroll
      for (int j = 0; j < 4; j++) {
        float u = acc[mi][ni][j] + ps[0];
        u = (u - ps[1]) * ps[2] + ps[3];
        res[j] = u + xv[j];
      }
      *(f4*)&out[idx] = res;
    }
}

// ---------------- launch ----------------
extern "C" void kernel_launch(void* const* d_in, const int* in_sizes, int n_in,
                              void* d_out, int out_size, void* d_ws, size_t ws_size,
                              hipStream_t stream) {
  const float* x  = (const float*)d_in[0];
  const float* wq = (const float*)d_in[1];
  const float* qg = (const float*)d_in[2];
  const float* qb = (const float*)d_in[3];
  const float* qm = (const float*)d_in[4];
  const float* qv = (const float*)d_in[5];
  const float* wk = (const float*)d_in[6];
  const float* kg = (const float*)d_in[7];
  const float* kb = (const float*)d_in[8];
  const float* km = (const float*)d_in[9];
  const float* kv = (const float*)d_in[10];
  const float* wv = (const float*)d_in[11];
  const float* vg = (const float*)d_in[12];
  const float* vb = (const float*)d_in[13];
  const float* vm = (const float*)d_in[14];
  const float* vv = (const float*)d_in[15];
  const float* wp = (const float*)d_in[16];
  const float* bp = (const float*)d_in[17];
  const float* pg = (const float*)d_in[18];
  const float* pb = (const float*)d_in[19];
  const float* pm = (const float*)d_in[20];
  const float* pv = (const float*)d_in[21];

  char* w = (char*)d_ws;
  u16*  XS    = (u16*)(w + 0);                    // 16 MiB (T,B,N,C) bf16
  u16*  QS    = (u16*)(w + 16777216);             // 16 MiB (T*M2, 512) q spikes
  u16*  WCAT  = (u16*)(w + 33554432);             // 3 MiB branch-interleaved
  u16*  WPCAT = (u16*)(w + 36700160);             // 1 MiB
  float* BNS  = (float*)(w + 37748736);           // 24 KiB (interleaved rows)
  float* PSS  = (float*)(w + 37773312);           // 8 KiB
  int*   KVP  = (int*)(w + 37781504);             // 256 KiB (tb,half,512)

  float* out  = (float*)d_out;                    // (T,B,C,N) f32
  float* vout = out + 8388608;                    // (T,B,8,N,64) f32

  k_prep_lif<<<4616, 256, 0, stream>>>(x, XS, wq, wk, wv, wp,
                                       qg, qb, qm, qv, kg, kb, km, kv,
                                       vg, vb, vm, vv, pg, pb, pm, pv, bp,
                                       WCAT, WPCAT, BNS, PSS);
  k_qkv_gemm<<<dim3(32, 16), 256, 0, stream>>>(XS, WCAT, BNS, QS, vout, KVP);
  k_proj_gemm<<<dim3(128, 8), 256, 0, stream>>>(QS, KVP, WPCAT, PSS, x, out);
}

// Round 8
// 198.153 us; speedup vs baseline: 1.2066x; 1.2066x over previous
//
#include <hip/hip_runtime.h>
#include <hip/hip_bf16.h>

typedef unsigned short u16;
typedef unsigned int u32;
typedef __attribute__((ext_vector_type(8))) short bh8;   // 8 bf16 (MFMA A/B frag)
typedef __attribute__((ext_vector_type(4))) short sh4;   // 4 bf16 (8B store)
typedef __attribute__((ext_vector_type(4))) float f4;    // MFMA C/D frag

#define T_   4
#define B_   16
#define C_   512
#define N_   256
#define M2_  4096

// ---------------- helpers ----------------
__device__ __forceinline__ u16 f2bf(float f) {
  u32 u = __float_as_uint(f);
  u32 r = (u + 0x7FFFu + ((u >> 16) & 1u)) >> 16;   // RNE
  return (u16)r;
}
__device__ __forceinline__ void gl_lds16(const void* g, void* l) {
  __builtin_amdgcn_global_load_lds(
      (const __attribute__((address_space(1))) unsigned int*)g,
      (__attribute__((address_space(3))) unsigned int*)l, 16, 0, 0);
}

// ---------------- K0: merged {weight split (branch-interleaved) + BN consts} + {shortcut LIF} ----------------
// WCAT row layout: rI = (o/32)*96 + branch*32 + (o%32)  -> each 96-row tile = {q,k,v} x 32 channels
__global__ void k_prep_lif(const float* __restrict__ x, u16* __restrict__ xs,
                           const float* __restrict__ wq, const float* __restrict__ wk,
                           const float* __restrict__ wv, const float* __restrict__ wp,
                           const float* qg, const float* qb, const float* qm, const float* qv,
                           const float* kg, const float* kb, const float* km, const float* kv2,
                           const float* vg, const float* vb, const float* vm, const float* vv,
                           const float* pg, const float* pb, const float* pm, const float* pv,
                           const float* bp,
                           u16* __restrict__ wcat, u16* __restrict__ wpcat,
                           float* bns, float* pss) {
  __shared__ u16 sp[4][64][68];
  int bid = blockIdx.x;
  int tid = threadIdx.x;
  if (bid < 512) {
    int b = bid >> 5, c0 = ((bid >> 2) & 7) * 64, n0 = (bid & 3) * 64;
    int rq = tid >> 4;
    int n4 = (tid & 15) * 4;
    f4 xr[4][4];
#pragma unroll
    for (int t = 0; t < 4; t++) {
      const float* xb = x + (((size_t)t * 16 + b) * 512 + c0) * 256 + n0;
#pragma unroll
      for (int i = 0; i < 4; i++)
        xr[t][i] = *(const f4*)(xb + (size_t)(rq + i * 16) * 256 + n4);
    }
    float v[16];
#pragma unroll
    for (int i = 0; i < 16; i++) v[i] = 0.f;
#pragma unroll
    for (int t = 0; t < 4; t++) {
#pragma unroll
      for (int i = 0; i < 4; i++) {
        int row = rq + i * 16;
        sh4 sv;
#pragma unroll
        for (int j = 0; j < 4; j++) {
          float vv2 = v[i * 4 + j];
          vv2 = vv2 + (xr[t][i][j] - vv2) * 0.5f;
          u16 s = 0;
          if (vv2 >= 1.0f) { s = 0x3F80; vv2 = 0.f; }
          v[i * 4 + j] = vv2;
          sv[j] = (short)s;
        }
        *(sh4*)&sp[t][row][n4] = sv;
      }
    }
    __syncthreads();
    int cp = (tid & 31) * 2;
    int nq = tid >> 5;
    for (int t = 0; t < 4; t++) {
      u16* ob = xs + (((size_t)t * 16 + b) * 256 + n0) * 512 + c0;
#pragma unroll
      for (int i = 0; i < 8; i++) {
        int n = nq + i * 8;
        u32 w = (u32)sp[t][cp][n] | ((u32)sp[t][cp + 1][n] << 16);
        *(u32*)(ob + (size_t)n * 512 + cp) = w;
      }
    }
  } else {
    int id = (bid - 512) * 256 + tid;
    if (id < 1048576) {
      int mat = id >> 18;
      int rc  = id & 262143;
      int o = rc >> 9, c = rc & 511;
      const float* src = (mat == 0) ? wq : (mat == 1) ? wk : (mat == 2) ? wv : wp;
      float w = src[rc];
      u16 hu = f2bf(w);
      float hf = __uint_as_float(((u32)hu) << 16);
      u16 lu = f2bf(w - hf);
      if (mat < 3) {
        int rI = (o >> 5) * 96 + mat * 32 + (o & 31);   // branch-interleaved row
        size_t base = (size_t)rI * 1024 + c;
        wcat[base] = hu; wcat[base + 512] = lu;
      } else {
        size_t base = (size_t)o * 1024 + c;
        wpcat[base] = hu; wpcat[base + 512] = lu;
      }
    } else {
      int j = id - 1048576;
      if (j < 1536) {
        int br = j >> 9, o = j & 511;
        const float *g, *b, *m, *va;
        if (br == 0)      { g = qg; b = qb; m = qm; va = qv; }
        else if (br == 1) { g = kg; b = kb; m = km; va = kv2; }
        else              { g = vg; b = vb; m = vm; va = vv; }
        float s = g[o] / sqrtf(va[o] + 1e-5f);
        int rI = (o >> 5) * 96 + br * 32 + (o & 31);
        bns[rI * 4 + 0] = s; bns[rI * 4 + 1] = m[o]; bns[rI * 4 + 2] = b[o];
        bns[rI * 4 + 3] = 0.f;
      } else if (j < 2048) {
        int c = j - 1536;
        float s = pg[c] / sqrtf(pv[c] + 1e-5f);
        pss[c * 4 + 0] = bp[c]; pss[c * 4 + 1] = pm[c];
        pss[c * 4 + 2] = s;     pss[c * 4 + 3] = pb[c];
      }
    }
  }
}

// ---------------- K2: fused QKV GEMM + BN + LIF + kv-count + vout ----------------
// 128x96 tile, BK=64, dbuf 2x40KB, T3-minimum pipeline (r4/r6 proven).
// Wave split: mw = wid&1 (64-row m-half), wn = wid>>1 (channel parity).
// Subtile sI = ni*2 + wn: ni=0 -> q, ni=1 -> k, ni=2 -> v (16 channels each).
// Reads/step/wave: 20 frags (vs r6's 28); acc 48 + vst 48 regs (same as r6, no spill).
__launch_bounds__(256, 2)
__global__ void k_qkv_gemm(const u16* __restrict__ xs, const u16* __restrict__ wcat,
                           const float* __restrict__ bns,
                           u16* __restrict__ qs, float* __restrict__ vout,
                           int* __restrict__ kvp) {
  __shared__ char lds[81920];   // buf: A 16K | Bh 12K | Bl 12K ; x2
  int tid = threadIdx.x, lane = tid & 63;
  int wid = tid >> 6;
  int mw = wid & 1, wn = wid >> 1;
  int lr = lane & 15, lq = lane >> 4;
  int m0 = blockIdx.x * 128;
  int cb = blockIdx.y;
  int o0 = cb * 96;
  int b = m0 >> 8, n0 = m0 & 255, half = (m0 >> 7) & 1;

  float scl[3], mn[3], bt[3];
#pragma unroll
  for (int ni = 0; ni < 3; ni++) {
    int rI = o0 + (ni * 2 + wn) * 16 + lr;
    scl[ni] = bns[rI * 4]; mn[ni] = bns[rI * 4 + 1]; bt[ni] = bns[rI * 4 + 2];
  }

  int srow = tid >> 3;
  u32 sgoff = (u32)(((tid & 7) ^ (srow & 7)) << 4);
  u32 ldst = (u32)tid * 16;

  u32 aoff[4], boff[3];
#pragma unroll
  for (int mi = 0; mi < 4; mi++) {
    int r = mw * 64 + mi * 16 + lr;
    aoff[mi] = r * 128 + ((lq ^ (r & 7)) << 4);
  }
#pragma unroll
  for (int ni = 0; ni < 3; ni++) {
    int r = (ni * 2 + wn) * 16 + lr;
    boff[ni] = r * 128 + ((lq ^ (r & 7)) << 4);
  }

  const char* Bb = (const char*)wcat + (size_t)o0 * 2048;

  auto STAGE = [&](int buf, int step) {
    int t = step >> 3;
    u32 kb = (u32)(step & 7) * 128;
    const char* Ab = (const char*)xs + ((size_t)t * M2_ + m0) * 1024;
    char* L = lds + buf * 40960;
#pragma unroll
    for (int r2 = 0; r2 < 4; r2++)
      gl_lds16(Ab + (size_t)(r2 * 32 + srow) * 1024 + kb + sgoff, L + r2 * 4096 + ldst);
#pragma unroll
    for (int r2 = 0; r2 < 3; r2++) {
      gl_lds16(Bb + (size_t)(r2 * 32 + srow) * 2048 + kb + sgoff, L + 16384 + r2 * 4096 + ldst);
      gl_lds16(Bb + (size_t)(r2 * 32 + srow) * 2048 + 1024 + kb + sgoff, L + 28672 + r2 * 4096 + ldst);
    }
  };

  float vst[4][3][4];
#pragma unroll
  for (int a = 0; a < 4; a++)
#pragma unroll
    for (int bq = 0; bq < 3; bq++)
#pragma unroll
      for (int c = 0; c < 4; c++) vst[a][bq][c] = 0.f;

  f4 acc[4][3];
  STAGE(0, 0);
  __syncthreads();                 // drain prologue stage
  int cur = 0;
  for (int step = 0; step < 32; ++step) {
    int ks = step & 7;
    if (ks == 0) {
#pragma unroll
      for (int a = 0; a < 4; a++)
#pragma unroll
        for (int bq = 0; bq < 3; bq++) { acc[a][bq][0] = 0.f; acc[a][bq][1] = 0.f; acc[a][bq][2] = 0.f; acc[a][bq][3] = 0.f; }
    }
    if (step < 31) STAGE(cur ^ 1, step + 1);   // next-tile loads in flight across MFMAs
    const char* L = lds + cur * 40960;
#pragma unroll
    for (int h = 0; h < 2; h++) {
      u32 hx = (u32)h << 6;
      bh8 af[4], bf[3], lf[3];
#pragma unroll
      for (int mi = 0; mi < 4; mi++)
        af[mi] = *(const bh8*)(L + (aoff[mi] ^ hx));
#pragma unroll
      for (int ni = 0; ni < 3; ni++) {
        bf[ni] = *(const bh8*)(L + 16384 + (boff[ni] ^ hx));
        lf[ni] = *(const bh8*)(L + 28672 + (boff[ni] ^ hx));
      }
#pragma unroll
      for (int mi = 0; mi < 4; mi++)
#pragma unroll
        for (int ni = 0; ni < 3; ni++)
          acc[mi][ni] = __builtin_amdgcn_mfma_f32_16x16x32_bf16(af[mi], bf[ni], acc[mi][ni], 0, 0, 0);
#pragma unroll
      for (int mi = 0; mi < 4; mi++)
#pragma unroll
        for (int ni = 0; ni < 3; ni++)
          acc[mi][ni] = __builtin_amdgcn_mfma_f32_16x16x32_bf16(af[mi], lf[ni], acc[mi][ni], 0, 0, 0);
    }
    asm volatile("s_waitcnt vmcnt(0)" ::: "memory");   // next-tile loads landed
    __builtin_amdgcn_s_barrier();
    cur ^= 1;
    if (ks == 7) {
      int t = step >> 3;
      char* dead = lds + (cur ^ 1) * 40960;   // just-read buffer (free scratch)
      unsigned char* vbuf = (unsigned char*)dead;           // [128][32] u8
      short* cbuf = (short*)(dead + 4096);                  // [256]
      int cnt = 0;
      u32 kbits = 0;
#pragma unroll
      for (int ni = 0; ni < 3; ni++) {
#pragma unroll
        for (int mi = 0; mi < 4; mi++) {
#pragma unroll
          for (int j = 0; j < 4; j++) {
            float y = (acc[mi][ni][j] - mn[ni]) * scl[ni] + bt[ni];
            float vv = vst[mi][ni][j];
            vv = vv + (y - vv) * 0.5f;
            int s = (vv >= 1.0f) ? 1 : 0;
            if (s) vv = 0.f;
            vst[mi][ni][j] = vv;
            if (ni == 0) {                // q spikes -> QS
              int rg = m0 + mw * 64 + mi * 16 + lq * 4 + j;
              qs[((size_t)t * M2_ + rg) * 512 + cb * 32 + wn * 16 + lr] = s ? (u16)0x3F80 : (u16)0;
            } else if (ni == 1) {         // k spikes -> bits
              kbits |= (u32)s << (mi * 4 + j);
            } else {                      // v spikes -> vbuf + kv count
              int row = mw * 64 + mi * 16 + lq * 4 + j;
              vbuf[row * 32 + wn * 16 + lr] = (unsigned char)s;
              cnt += s & (int)((kbits >> (mi * 4 + j)) & 1);
            }
          }
        }
      }
      cbuf[tid] = (short)cnt;
      asm volatile("s_waitcnt lgkmcnt(0)" ::: "memory");
      __builtin_amdgcn_s_barrier();
      // ---- phase B: coalesced vout flush + kv partial write ----
      {
        int d0 = (cb & 1) * 32;
        int hh = cb >> 1;
        float* vo = vout + (((size_t)(t * 16 + b) * 8 + hh) * 256 + n0) * 64 + d0;
#pragma unroll
        for (int p = 0; p < 4; p++) {
          int row = (tid >> 3) + p * 32;
          const unsigned char* src = vbuf + row * 32 + (tid & 7) * 4;
          f4 w2; w2[0] = src[0]; w2[1] = src[1]; w2[2] = src[2]; w2[3] = src[3];
          *(f4*)(vo + (size_t)row * 64 + (tid & 7) * 4) = w2;
        }
        if (tid < 32) {
          int lr2 = tid & 15, wn2 = tid >> 4;
          int ssum = 0;
#pragma unroll
          for (int mw2 = 0; mw2 < 2; mw2++)
#pragma unroll
            for (int lq2 = 0; lq2 < 4; lq2++)
              ssum += cbuf[((wn2 * 2 + mw2) << 6) + lq2 * 16 + lr2];
          kvp[(((t * 16 + b) * 2 + half) << 9) + cb * 32 + wn2 * 16 + lr2] = ssum;
        }
      }
      asm volatile("s_waitcnt lgkmcnt(0)" ::: "memory");
      __builtin_amdgcn_s_barrier();
    }
  }
}

// ---------------- K5: proj GEMM with in-block talking-heads LIF mask + fused epilogue ----------------
__launch_bounds__(256, 2)
__global__ void k_proj_gemm(const u16* __restrict__ qs, const int* __restrict__ kvp,
                            const u16* __restrict__ wpc, const float* __restrict__ pss,
                            const float* __restrict__ x, float* __restrict__ out) {
  __shared__ char lds[66560];   // buf: A 16K | Bh 8K | Bl 8K ; x2 = 64K ; lm at 65536
  u16* lm = (u16*)(lds + 65536);
  int tid = threadIdx.x, lane = tid & 63, wid = tid >> 6;
  int wr = wid >> 1, wc = wid & 1, lr = lane & 15, lq = lane >> 4;
  int m0 = blockIdx.x * 128, o0 = blockIdx.y * 64;
  int tb = m0 >> 8;

  // in-block talking-heads LIF: recompute mask for this tb from KVP partials
  {
    int b_ = tb & 15, tt = tb >> 4;
#pragma unroll
    for (int ci = 0; ci < 2; ci++) {
      int cc = tid + ci * 256;
      float v = 0.f; u16 mk = 0;
#pragma unroll
      for (int t2 = 0; t2 < 4; t2++) {
        int tb2 = t2 * 16 + b_;
        int s = kvp[((tb2 * 2) << 9) + cc] + kvp[((tb2 * 2 + 1) << 9) + cc];
        v = v + ((float)s - v) * 0.5f;
        int sp = (v >= 0.5f) ? 1 : 0;
        if (sp) v = 0.f;
        if (t2 == tt) mk = sp ? (u16)0xFFFF : (u16)0;
      }
      lm[cc] = mk;
    }
  }

  int srow = tid >> 3;
  u32 sgoff = (u32)(((tid & 7) ^ (srow & 7)) << 4);
  u32 ldst = (u32)tid * 16;

  u32 aoff[4], boff[2];
#pragma unroll
  for (int mi = 0; mi < 4; mi++) {
    int r = wr * 64 + mi * 16 + lr;
    aoff[mi] = r * 128 + ((lq ^ (r & 7)) << 4);
  }
#pragma unroll
  for (int ni = 0; ni < 2; ni++) {
    int r = wc * 32 + ni * 16 + lr;
    boff[ni] = r * 128 + ((lq ^ (r & 7)) << 4);
  }

  const char* Ab = (const char*)qs + (size_t)m0 * 1024;
  const char* Bb = (const char*)wpc + (size_t)o0 * 2048;

  auto STAGE = [&](int buf, int step) {
    u32 kb = (u32)step * 128;
    char* L = lds + buf * 32768;
#pragma unroll
    for (int r2 = 0; r2 < 4; r2++)
      gl_lds16(Ab + (size_t)(r2 * 32 + srow) * 1024 + kb + sgoff, L + r2 * 4096 + ldst);
#pragma unroll
    for (int r2 = 0; r2 < 2; r2++) {
      gl_lds16(Bb + (size_t)(r2 * 32 + srow) * 2048 + kb + sgoff, L + 16384 + r2 * 4096 + ldst);
      gl_lds16(Bb + (size_t)(r2 * 32 + srow) * 2048 + 1024 + kb + sgoff, L + 24576 + r2 * 4096 + ldst);
    }
  };

  f4 acc[4][2];
#pragma unroll
  for (int a = 0; a < 4; a++)
#pragma unroll
    for (int b2 = 0; b2 < 2; b2++) { acc[a][b2][0] = 0.f; acc[a][b2][1] = 0.f; acc[a][b2][2] = 0.f; acc[a][b2][3] = 0.f; }

  STAGE(0, 0);
  __syncthreads();                 // drain prologue stage + publish lm
  int cur = 0;
  for (int step = 0; step < 8; ++step) {
    u32 kb = (u32)step * 128;
    if (step < 7) STAGE(cur ^ 1, step + 1);
    const char* L = lds + cur * 32768;
#pragma unroll
    for (int h = 0; h < 2; h++) {
      u32 hx = (u32)h << 6;
      bh8 mq = *(const bh8*)((const char*)lm + kb + (h << 6) + lq * 16);
      bh8 af[4], bf[2], lf[2];
#pragma unroll
      for (int mi = 0; mi < 4; mi++) {
        af[mi] = *(const bh8*)(L + (aoff[mi] ^ hx));
        af[mi] = af[mi] & mq;
      }
#pragma unroll
      for (int ni = 0; ni < 2; ni++) {
        bf[ni] = *(const bh8*)(L + 16384 + (boff[ni] ^ hx));
        lf[ni] = *(const bh8*)(L + 24576 + (boff[ni] ^ hx));
      }
#pragma unroll
      for (int mi = 0; mi < 4; mi++)
#pragma unroll
        for (int ni = 0; ni < 2; ni++)
          acc[mi][ni] = __builtin_amdgcn_mfma_f32_16x16x32_bf16(af[mi], bf[ni], acc[mi][ni], 0, 0, 0);
#pragma unroll
      for (int mi = 0; mi < 4; mi++)
#pragma unroll
        for (int ni = 0; ni < 2; ni++)
          acc[mi][ni] = __builtin_amdgcn_mfma_f32_16x16x32_bf16(af[mi], lf[ni], acc[mi][ni], 0, 0, 0);
    }
    asm volatile("s_waitcnt vmcnt(0)" ::: "memory");
    __builtin_amdgcn_s_barrier();
    cur ^= 1;
  }
  // fused epilogue: BN(y + bp) + identity, transposed store to out[tb][o][n]
#pragma unroll
  for (int mi = 0; mi < 4; mi++)
#pragma unroll
    for (int ni = 0; ni < 2; ni++) {
      int o = o0 + wc * 32 + ni * 16 + lr;
      f4 ps = *(const f4*)&pss[o * 4];        // {bp, pm, scale, beta}
      int n = (m0 & 255) + wr * 64 + mi * 16 + lq * 4;
      size_t idx = (size_t)tb * 131072 + (size_t)o * 256 + n;
      f4 xv = *(const f4*)&x[idx];
      f4 res;
#pragma unroll
      for (int j = 0; j < 4; j++) {
        float u = acc[mi][ni][j] + ps[0];
        u = (u - ps[1]) * ps[2] + ps[3];
        res[j] = u + xv[j];
      }
      *(f4*)&out[idx] = res;
    }
}

// ---------------- launch ----------------
extern "C" void kernel_launch(void* const* d_in, const int* in_sizes, int n_in,
                              void* d_out, int out_size, void* d_ws, size_t ws_size,
                              hipStream_t stream) {
  const float* x  = (const float*)d_in[0];
  const float* wq = (const float*)d_in[1];
  const float* qg = (const float*)d_in[2];
  const float* qb = (const float*)d_in[3];
  const float* qm = (const float*)d_in[4];
  const float* qv = (const float*)d_in[5];
  const float* wk = (const float*)d_in[6];
  const float* kg = (const float*)d_in[7];
  const float* kb = (const float*)d_in[8];
  const float* km = (const float*)d_in[9];
  const float* kv = (const float*)d_in[10];
  const float* wv = (const float*)d_in[11];
  const float* vg = (const float*)d_in[12];
  const float* vb = (const float*)d_in[13];
  const float* vm = (const float*)d_in[14];
  const float* vv = (const float*)d_in[15];
  const float* wp = (const float*)d_in[16];
  const float* bp = (const float*)d_in[17];
  const float* pg = (const float*)d_in[18];
  const float* pb = (const float*)d_in[19];
  const float* pm = (const float*)d_in[20];
  const float* pv = (const float*)d_in[21];

  char* w = (char*)d_ws;
  u16*  XS    = (u16*)(w + 0);                    // 16 MiB (T,B,N,C) bf16
  u16*  QS    = (u16*)(w + 16777216);             // 16 MiB (T*M2, 512) q spikes
  u16*  WCAT  = (u16*)(w + 33554432);             // 3 MiB branch-interleaved
  u16*  WPCAT = (u16*)(w + 36700160);             // 1 MiB
  float* BNS  = (float*)(w + 37748736);           // 24 KiB (interleaved rows)
  float* PSS  = (float*)(w + 37773312);           // 8 KiB
  int*   KVP  = (int*)(w + 37781504);             // 256 KiB (tb,half,512)

  float* out  = (float*)d_out;                    // (T,B,C,N) f32
  float* vout = out + 8388608;                    // (T,B,8,N,64) f32

  k_prep_lif<<<4616, 256, 0, stream>>>(x, XS, wq, wk, wv, wp,
                                       qg, qb, qm, qv, kg, kb, km, kv,
                                       vg, vb, vm, vv, pg, pb, pm, pv, bp,
                                       WCAT, WPCAT, BNS, PSS);
  k_qkv_gemm<<<dim3(32, 16), 256, 0, stream>>>(XS, WCAT, BNS, QS, vout, KVP);
  k_proj_gemm<<<dim3(128, 8), 256, 0, stream>>>(QS, KVP, WPCAT, PSS, x, out);
}